// Round 4
// baseline (923.701 us; speedup 1.0000x reference)
//
#include <hip/hip_runtime.h>

// ---------------------------------------------------------------------------
// TTT base module: out = (scan(XC,XB,XA,coeff) ) @ Wo^T
//   GEMM v3: 128x128 tile, BK=32, 3-buffer depth-2 pipeline, counted
//     vmcnt(4) (never 0 mid-loop) + one barrier per K-step (T4 recipe).
//   Scan v5: 4 waves, feature-split; 2 barriers/chunk:
//     - LN1+grad reductions merged into one 6-sum stage (algebraic identity)
//     - sW1 is wave-private (no barrier); stage(c+1)+LN2 share one barrier
// ---------------------------------------------------------------------------

typedef __attribute__((ext_vector_type(4))) float float4v;
typedef __attribute__((ext_vector_type(2))) float float2v;
typedef __attribute__((ext_vector_type(8))) __bf16 bf16x8;
typedef __attribute__((ext_vector_type(4))) short short4v;
typedef __attribute__((ext_vector_type(4))) unsigned int uint4v;
typedef __attribute__((ext_vector_type(2))) unsigned int uint2v;

__device__ __forceinline__ unsigned short f2bf(float f) {
  unsigned int u = __builtin_bit_cast(unsigned int, f);
  u += 0x7FFFu + ((u >> 16) & 1u);
  return (unsigned short)(u >> 16);
}
__device__ __forceinline__ float bf2f(unsigned short s) {
  unsigned int u = ((unsigned int)s) << 16;
  return __builtin_bit_cast(float, u);
}
__device__ __forceinline__ void lds_load16(const void* g, void* l) {
  __builtin_amdgcn_global_load_lds((const __attribute__((address_space(1))) void*)g,
                                   (__attribute__((address_space(3))) void*)l, 16, 0, 0);
}

__device__ __forceinline__ void store_out(float* p, float v) { *p = v; }
__device__ __forceinline__ void store_out(unsigned short* p, float v) { *p = f2bf(v); }

// DPP helpers: VALU-speed cross-lane moves within 16-lane rows.
template <int CTRL>
__device__ __forceinline__ float dppmov(float x) {
  return __builtin_bit_cast(
      float, __builtin_amdgcn_update_dpp(0, __builtin_bit_cast(int, x), CTRL, 0xF, 0xF, true));
}
// Sum over the 16 lanes of a DPP row; result in all 16 lanes.
__device__ __forceinline__ float red16(float x) {
  x += dppmov<0xB1>(x);   // quad_perm [1,0,3,2]  (xor 1)
  x += dppmov<0x4E>(x);   // quad_perm [2,3,0,1]  (xor 2)
  x += dppmov<0x124>(x);  // row_ror:4
  x += dppmov<0x128>(x);  // row_ror:8
  return x;
}
__device__ __forceinline__ unsigned int cvtpk_bf16(float lo, float hi) {
  unsigned int r;
  asm("v_cvt_pk_bf16_f32 %0, %1, %2" : "=v"(r) : "v"(lo), "v"(hi));
  return r;
}
// Raw workgroup barrier: waits only LDS ops (lgkmcnt), NOT vmcnt -> in-flight
// global prefetch survives the barrier.
__device__ __forceinline__ void bar_sync() {
  asm volatile("s_waitcnt lgkmcnt(0)" ::: "memory");
  __builtin_amdgcn_s_barrier();
  asm volatile("" ::: "memory");
}

// ---------------------------------------------------------------------------
// C[m,n] = sum_k A[m,k] * B[n,k]   (A: MxK bf16, B: NxK bf16 row-major)
// 128x128 tile, BK=32, 256 threads = 4 waves (2x2 of 64x64), 16x16x32 MFMA.
// 3-buffer depth-2 pipeline: stage(i+2) issued at step i; vmcnt(4) before the
// per-step barrier (loads for i+1 stay in flight across it).
// ---------------------------------------------------------------------------
template <typename OUT>
__global__ __launch_bounds__(256) void gemm_bt(
    const unsigned short* __restrict__ A, const unsigned short* __restrict__ B,
    OUT* __restrict__ C, int M, int N, int K) {
  __shared__ unsigned short sA[3][128 * 32];
  __shared__ unsigned short sB[3][128 * 32];
  const int tid = threadIdx.x;
  const int wave = tid >> 6;
  const int lane = tid & 63;
  const int quad = lane >> 4;
  const int l15 = lane & 15;
  const int wm = (wave >> 1) * 64;
  const int wn = (wave & 1) * 64;
  const int bm = blockIdx.y * 128;
  const int bn = blockIdx.x * 128;

  float4v acc[4][4];
#pragma unroll
  for (int i = 0; i < 4; ++i)
#pragma unroll
    for (int j = 0; j < 4; ++j) acc[i][j] = (float4v){0.f, 0.f, 0.f, 0.f};

  const int srow = tid >> 2;
  const int scol = (tid & 3) * 8;
  const unsigned short* aptr = A + (size_t)(bm + srow) * K + scol;
  const unsigned short* bptr = B + (size_t)(bn + srow) * K + scol;
  const size_t astep = (size_t)64 * K;
  const int woff = wave * 512;
  const int nsteps = K >> 5;

#define GSTAGE(t, bi)                                                   \
  {                                                                     \
    lds_load16(aptr + (size_t)(t) * 32, &sA[bi][woff]);                 \
    lds_load16(aptr + (size_t)(t) * 32 + astep, &sA[bi][2048 + woff]);  \
    lds_load16(bptr + (size_t)(t) * 32, &sB[bi][woff]);                 \
    lds_load16(bptr + (size_t)(t) * 32 + astep, &sB[bi][2048 + woff]);  \
  }

  // prologue: stage tiles 0 and 1
  GSTAGE(0, 0);
  if (nsteps > 1) GSTAGE(1, 1);

  for (int i = 0; i < nsteps; ++i) {
    // wait own stage(i) loads (counted: loads for i+1 stay in flight), then
    // barrier -> all waves' stage(i) writes visible; prior reads drained.
    if (i + 1 < nsteps) {
      asm volatile("s_waitcnt vmcnt(4)" ::: "memory");
    } else {
      asm volatile("s_waitcnt vmcnt(0)" ::: "memory");
    }
    __builtin_amdgcn_s_barrier();
    asm volatile("" ::: "memory");
    if (i + 2 < nsteps) {
      const int bi = (i + 2) % 3;
      GSTAGE(i + 2, bi);
    }
    const int cb = i % 3;
    bf16x8 af[4], bf[4];
#pragma unroll
    for (int ii = 0; ii < 4; ++ii)
      af[ii] = *(const bf16x8*)&sA[cb][(wm + ii * 16 + l15) * 32 + quad * 8];
#pragma unroll
    for (int j = 0; j < 4; ++j)
      bf[j] = *(const bf16x8*)&sB[cb][(wn + j * 16 + l15) * 32 + quad * 8];
#pragma unroll
    for (int ii = 0; ii < 4; ++ii)
#pragma unroll
      for (int j = 0; j < 4; ++j)
        acc[ii][j] = __builtin_amdgcn_mfma_f32_16x16x32_bf16(af[ii], bf[j], acc[ii][j], 0, 0, 0);
  }
#undef GSTAGE

#pragma unroll
  for (int i = 0; i < 4; ++i) {
    const int row0 = bm + wm + i * 16 + quad * 4;
#pragma unroll
    for (int j = 0; j < 4; ++j) {
      const int col = bn + wn + j * 16 + l15;
#pragma unroll
      for (int r = 0; r < 4; ++r)
        store_out(&C[(size_t)(row0 + r) * N + col], acc[i][j][r]);
    }
  }
}

// ---------------------------------------------------------------------------
__global__ __launch_bounds__(256) void f32_to_bf16_k(const float* __restrict__ s,
                                                     unsigned short* __restrict__ d, int n) {
  const int i = (blockIdx.x * 256 + threadIdx.x) * 8;
  if (i >= n) return;
  const float4v a = *(const float4v*)(s + i);
  const float4v b = *(const float4v*)(s + i + 4);
  uint4v o;
  o[0] = (unsigned int)f2bf(a[0]) | ((unsigned int)f2bf(a[1]) << 16);
  o[1] = (unsigned int)f2bf(a[2]) | ((unsigned int)f2bf(a[3]) << 16);
  o[2] = (unsigned int)f2bf(b[0]) | ((unsigned int)f2bf(b[1]) << 16);
  o[3] = (unsigned int)f2bf(b[2]) | ((unsigned int)f2bf(b[3]) << 16);
  *(uint4v*)(d + i) = o;
}

// ---------------------------------------------------------------------------
// coeff[b,h,c,k] = sigmoid(ilr[row,h] + lb[h]) / (64*(k+1))
// ---------------------------------------------------------------------------
__global__ __launch_bounds__(256) void coeff_k(const unsigned short* __restrict__ ilr,
                                               const float* __restrict__ lb,
                                               float* __restrict__ coeff) {
  const int gid = blockIdx.x * 256 + threadIdx.x;
  const int row = gid >> 5;
  const int h = gid & 31;
  const float v = bf2f(ilr[row * 128 + h]) + lb[h];
  const float sig = 1.0f / (1.0f + __expf(-v));
  const int b = row >> 11;
  const int pos = row & 2047;
  const int cc = pos >> 4;
  const int k = pos & 15;
  coeff[((((size_t)b * 32 + h) * 128 + cc) << 4) + k] = sig / (64.0f * (float)(k + 1));
}

// ---------------------------------------------------------------------------
// TTT scan v5: one block = one (b,h); 4 waves; 128 sequential chunks of K=16.
// Wave w owns features w*16..w*16+15. Two barriers per chunk.
// ---------------------------------------------------------------------------
__global__ __launch_bounds__(256, 1) void ttt_scan(
    const unsigned short* __restrict__ XC, const unsigned short* __restrict__ XB,
    const unsigned short* __restrict__ XA, const float* __restrict__ coeff,
    const float* __restrict__ lnw, const float* __restrict__ lnb,
    const float* __restrict__ W1i, const float* __restrict__ b1i,
    unsigned short* __restrict__ XCW) {
  const int b = blockIdx.x >> 5;
  const int h = blockIdx.x & 31;
  const int tid = threadIdx.x;
  const int wave = tid >> 6;
  const int lane = tid & 63;
  const int quad = lane >> 4;
  const int l15 = lane & 15;

  constexpr int LDW = 88;  // u16 stride: b128-aligned, max 2-way bank alias
  __shared__ __attribute__((aligned(16))) unsigned short sXC[2][16 * LDW];
  __shared__ __attribute__((aligned(16))) unsigned short sXB[2][16 * LDW];
  __shared__ __attribute__((aligned(16))) unsigned short sXA[2][16 * LDW];
  __shared__ __attribute__((aligned(16))) unsigned short sW1[64 * LDW];
  __shared__ __attribute__((aligned(16))) float sRedA[3][16][8];  // [pair][token][wave*2+{a,b}]
  __shared__ __attribute__((aligned(16))) float sRedB[16][8];
  __shared__ __attribute__((aligned(16))) float sA0[4];

  const int fcol = wave * 16 + l15;  // this lane's owned feature
  const float gam = lnw[h * 64 + fcol];
  const float bet = lnb[h * 64 + fcol];
  const float gam2 = gam * gam;

  // W1 columns owned by this wave: W1r[mt][r] = W1[mt*16+quad*4+r][fcol]
  float4v W1r[4];
#pragma unroll
  for (int mt = 0; mt < 4; ++mt) {
    float4v v;
#pragma unroll
    for (int r = 0; r < 4; ++r)
      v[r] = W1i[(size_t)h * 4096 + (size_t)(mt * 16 + quad * 4 + r) * 64 + fcol];
    W1r[mt] = v;
  }
  float b1v = b1i[h * 64 + fcol];

  // publish W1^T rows (wave-private: wave reads only rows wave*16..wave*16+15)
#pragma unroll
  for (int mt = 0; mt < 4; ++mt) {
    uint2v p;
    p[0] = cvtpk_bf16(W1r[mt][0], W1r[mt][1]);
    p[1] = cvtpk_bf16(W1r[mt][2], W1r[mt][3]);
    *(uint2v*)&sW1[(size_t)fcol * LDW + mt * 16 + quad * 4] = p;
  }

  // A0 = sum_f gam^2 (constant across chunks)
  {
    const float a0p = red16(gam2);
    if (lane == 0) sA0[wave] = a0p;
  }

  // staging: 16 rows x 8 col-chunks of 16B per tensor; threads 0-127 cover
  // XC+XA, threads 128-255 cover XB.
  const int u = tid & 127;
  const int grow = u >> 3;
  const int gcol = (u & 7) * 8;
  const size_t hdoff = (size_t)h * 64;
  const size_t browoff = (size_t)b * 2048;
  const float* cobase = coeff + (((size_t)b * 32 + h) * 128) * 16;
  const float inv64 = 1.0f / 64.0f;
  const float4v zero4 = {0.f, 0.f, 0.f, 0.f};

  uint4v pA = {0, 0, 0, 0}, pB = {0, 0, 0, 0};
  float4v cof, pcof;
  {
    // chunk 0: load + stage directly
    const size_t g0 = (browoff + (size_t)grow) * 2048 + hdoff + gcol;
    uint4v a0, b0 = {0, 0, 0, 0};
    if (tid < 128) {
      a0 = *(const uint4v*)(XC + g0);
      b0 = *(const uint4v*)(XA + g0);
    } else {
      a0 = *(const uint4v*)(XB + g0);
    }
    if (tid < 128) {
      *(uint4v*)&sXC[0][grow * LDW + gcol] = a0;
      *(uint4v*)&sXA[0][grow * LDW + gcol] = b0;
    } else {
      *(uint4v*)&sXB[0][grow * LDW + gcol] = a0;
    }
    cof = *(const float4v*)(cobase + quad * 4);
    // prefetch chunk 1
    const size_t g1 = (browoff + (size_t)(16 + grow)) * 2048 + hdoff + gcol;
    if (tid < 128) {
      pA = *(const uint4v*)(XC + g1);
      pB = *(const uint4v*)(XA + g1);
    } else {
      pA = *(const uint4v*)(XB + g1);
    }
    pcof = *(const float4v*)(cobase + 16 + quad * 4);
  }
  bar_sync();  // A0 partials + W1 publish + stage(0) visible
  const float4v a0v = *(const float4v*)sA0;
  const float A0 = a0v[0] + a0v[1] + a0v[2] + a0v[3];

  for (int c = 0; c < 128; ++c) {
    const int buf = c & 1;

    // ---- fragments (stage(c) bar'd; sW1 wave-private, in-wave ordered) ----
    bf16x8 xbf[2], xcf[2], w1f[2];
#pragma unroll
    for (int hh = 0; hh < 2; ++hh) {
      xbf[hh] = *(const bf16x8*)&sXB[buf][l15 * LDW + hh * 32 + quad * 8];
      xcf[hh] = *(const bf16x8*)&sXC[buf][l15 * LDW + hh * 32 + quad * 8];
      w1f[hh] = *(const bf16x8*)&sW1[(size_t)fcol * LDW + hh * 32 + quad * 8];
    }

    // ---- Attn^T = xb@xc^T: at[r] = Attn[l15][quad*4+r] ----
    float4v at = __builtin_amdgcn_mfma_f32_16x16x32_bf16(xbf[0], xcf[0], zero4, 0, 0, 0);
    at = __builtin_amdgcn_mfma_f32_16x16x32_bf16(xbf[1], xcf[1], at, 0, 0, 0);

    // ---- Z1 = xb@W1[:,wave cols] + b1 ----
    float4v z = __builtin_amdgcn_mfma_f32_16x16x32_bf16(xbf[0], w1f[0], zero4, 0, 0, 0);
    z = __builtin_amdgcn_mfma_f32_16x16x32_bf16(xbf[1], w1f[1], z, 0, 0, 0);
#pragma unroll
    for (int r = 0; r < 4; ++r) z[r] += b1v;

    // ---- merged 6-sum reduction stage ----
    float gbt[4];
#pragma unroll
    for (int r = 0; r < 4; ++r) {
      const int toff = (quad * 4 + r) * LDW + fcol;
      const float tgt = bf2f(sXA[buf][toff]) - bf2f(sXB[buf][toff]);
      gbt[r] = gam * (bet - tgt);
    }
#pragma unroll
    for (int r = 0; r < 4; ++r) {
      const float zz = z[r];
      const float s1 = red16(zz);
      const float s2 = red16(zz * zz);
      const float a1 = red16(gam2 * zz);
      const float a2 = red16(gam2 * zz * zz);
      const float c0 = red16(gbt[r]);
      const float c1 = red16(gbt[r] * zz);
      if (l15 == 0) {
        const int t = quad * 4 + r;
        *(float2v*)&sRedA[0][t][wave * 2] = (float2v){s1, s2};
        *(float2v*)&sRedA[1][t][wave * 2] = (float2v){a1, a2};
        *(float2v*)&sRedA[2][t][wave * 2] = (float2v){c0, c1};
      }
    }

    // ---- indep work before bar A: m1f, caf ----
    short4v m1f;
#pragma unroll
    for (int jj = 0; jj < 4; ++jj) {
      const int k = quad * 4 + jj;
      const float e = (k <= l15) ? cof[jj] : 0.0f;
      m1f[jj] = (short)f2bf(-(at[jj] + 1.0f) * e);
    }
    short4v caf[4];
#pragma unroll
    for (int mt = 0; mt < 4; ++mt)
#pragma unroll
      for (int jj = 0; jj < 4; ++jj)
        caf[mt][jj] =
            (short)f2bf(-cof[jj] * bf2f(sXB[buf][(quad * 4 + jj) * LDW + mt * 16 + l15]));

    bar_sync();  // bar A: 6-sum partials visible

    // ---- combine partials -> mu,rstd,sg,sgx -> grad ----
    float xh[4], grad[4];
    short4v gradb;
#pragma unroll
    for (int r = 0; r < 4; ++r) {
      const int t = quad * 4 + r;
      const float4v p0 = *(const float4v*)&sRedA[0][t][0];
      const float4v p0b = *(const float4v*)&sRedA[0][t][4];
      const float4v p1 = *(const float4v*)&sRedA[1][t][0];
      const float4v p1b = *(const float4v*)&sRedA[1][t][4];
      const float4v p2 = *(const float4v*)&sRedA[2][t][0];
      const float4v p2b = *(const float4v*)&sRedA[2][t][4];
      const float s1 = p0[0] + p0[2] + p0b[0] + p0b[2];
      const float s2 = p0[1] + p0[3] + p0b[1] + p0b[3];
      const float a1 = p1[0] + p1[2] + p1b[0] + p1b[2];
      const float a2 = p1[1] + p1[3] + p1b[1] + p1b[3];
      const float c0 = p2[0] + p2[2] + p2b[0] + p2b[2];
      const float c1 = p2[1] + p2[3] + p2b[1] + p2b[3];
      const float mu = s1 * inv64;
      const float rstd = rsqrtf(s2 * inv64 - mu * mu + 1e-6f);
      const float sg = rstd * (a1 - mu * A0) + c0;
      const float sgx =
          rstd * rstd * (a2 - 2.0f * mu * a1 + mu * mu * A0) + rstd * (c1 - mu * c0);
      xh[r] = (z[r] - mu) * rstd;
      const float gg = gam2 * xh[r] + gbt[r];
      grad[r] = (64.0f * gg - sg - xh[r] * sgx) * (rstd * inv64);
      gradb[r] = (short)f2bf(grad[r]);
    }

    // ---- Z1_bar = xc@W1 - ((Attn+1) o E)@grad + b1 (old b1) ----
    float4v zb = __builtin_amdgcn_mfma_f32_16x16x32_bf16(xcf[0], w1f[0], zero4, 0, 0, 0);
    zb = __builtin_amdgcn_mfma_f32_16x16x32_bf16(xcf[1], w1f[1], zb, 0, 0, 0);
    zb = __builtin_amdgcn_mfma_f32_16x16x16bf16_1k(m1f, gradb, zb, 0, 0, 0);
#pragma unroll
    for (int r = 0; r < 4; ++r) zb[r] += b1v;

    // ---- LN2 partials ----
#pragma unroll
    for (int r = 0; r < 4; ++r) {
      const float s1p = red16(zb[r]);
      const float s2p = red16(zb[r] * zb[r]);
      if (l15 == 0) *(float2v*)&sRedB[quad * 4 + r][wave * 2] = (float2v){s1p, s2p};
    }

    // ---- W1 update (MFMA), b1 update, W1 publish (wave-private) ----
#pragma unroll
    for (int mt = 0; mt < 4; ++mt)
      W1r[mt] = __builtin_amdgcn_mfma_f32_16x16x16bf16_1k(caf[mt], gradb, W1r[mt], 0, 0, 0);
    {
      float pb = cof[0] * grad[0] + cof[1] * grad[1] + cof[2] * grad[2] + cof[3] * grad[3];
      pb += __shfl_xor(pb, 16);
      pb += __shfl_xor(pb, 32);
      b1v -= pb;
    }
#pragma unroll
    for (int mt = 0; mt < 4; ++mt) {
      uint2v p;
      p[0] = cvtpk_bf16(W1r[mt][0], W1r[mt][1]);
      p[1] = cvtpk_bf16(W1r[mt][2], W1r[mt][3]);
      *(uint2v*)&sW1[(size_t)fcol * LDW + mt * 16 + quad * 4] = p;
    }

    // ---- stage chunk c+1 into buf^1 (prev reads drained at bar A) ----
    if (tid < 128) {
      *(uint4v*)&sXC[buf ^ 1][grow * LDW + gcol] = pA;
      *(uint4v*)&sXA[buf ^ 1][grow * LDW + gcol] = pB;
    } else {
      *(uint4v*)&sXB[buf ^ 1][grow * LDW + gcol] = pA;
    }
    // ---- issue prefetch chunk c+2; rotate coeff ----
    {
      const int cn = (c < 126) ? c + 2 : 127;
      const size_t goff = (browoff + (size_t)(cn * 16 + grow)) * 2048 + hdoff + gcol;
      if (tid < 128) {
        pA = *(const uint4v*)(XC + goff);
        pB = *(const uint4v*)(XA + goff);
      } else {
        pA = *(const uint4v*)(XB + goff);
      }
      cof = pcof;
      pcof = *(const float4v*)(cobase + (size_t)cn * 16 + quad * 4);
    }

    bar_sync();  // bar B: LN2 partials + stage(c+1) visible

    // ---- out = xc + LN(Z1_bar) ----
#pragma unroll
    for (int r = 0; r < 4; ++r) {
      const int t = quad * 4 + r;
      const float4v q0 = *(const float4v*)&sRedB[t][0];
      const float4v q1 = *(const float4v*)&sRedB[t][4];
      const float s1 = q0[0] + q0[2] + q1[0] + q1[2];
      const float s2 = q0[1] + q0[3] + q1[1] + q1[3];
      const float mu2 = s1 * inv64;
      const float rstd2 = rsqrtf(s2 * inv64 - mu2 * mu2 + 1e-6f);
      const float xhat = (zb[r] - mu2) * rstd2;
      const float y = gam * xhat + bet;
      const float o = bf2f(sXC[buf][t * LDW + fcol]) + y;
      XCW[(browoff + (size_t)(c * 16 + t)) * 2048 + hdoff + fcol] = f2bf(o);
    }
  }
}

// ---------------------------------------------------------------------------
extern "C" void kernel_launch(void* const* d_in, const int* in_sizes, int n_in,
                              void* d_out, int out_size, void* d_ws, size_t ws_size,
                              hipStream_t stream) {
  const float* hs = (const float*)d_in[0];
  const float* Wq = (const float*)d_in[1];
  const float* Wk = (const float*)d_in[2];
  const float* Wv = (const float*)d_in[3];
  const float* Wo = (const float*)d_in[4];
  const float* lw = (const float*)d_in[5];
  const float* lb = (const float*)d_in[6];
  const float* lnw = (const float*)d_in[7];
  const float* lnb = (const float*)d_in[8];
  const float* W1i = (const float*)d_in[9];
  const float* b1i = (const float*)d_in[10];
  float* out = (float*)d_out;
  char* ws = (char*)d_ws;

  unsigned short* hsb = (unsigned short*)(ws);               // 33554432 (hs bf16; reused as XCW)
  unsigned short* wqb = (unsigned short*)(ws + 33554432);    // 8388608
  unsigned short* wkb = (unsigned short*)(ws + 41943040);    // 8388608
  unsigned short* wvb = (unsigned short*)(ws + 50331648);    // 8388608
  unsigned short* wob = (unsigned short*)(ws + 58720256);    // 8388608
  unsigned short* lwb = (unsigned short*)(ws + 67108864);    // 524288
  unsigned short* XCb = (unsigned short*)(ws + 67633152);    // 33554432
  unsigned short* XBb = (unsigned short*)(ws + 101187584);   // 33554432
  unsigned short* XAb = (unsigned short*)(ws + 134742016);   // 33554432
  unsigned short* ilrb = (unsigned short*)(ws + 168296448);  // 2097152
  float* coeff = (float*)(ws + 170393600);                   // 1048576

  f32_to_bf16_k<<<8192, 256, 0, stream>>>(hs, hsb, 16777216);
  f32_to_bf16_k<<<2048, 256, 0, stream>>>(Wq, wqb, 4194304);
  f32_to_bf16_k<<<2048, 256, 0, stream>>>(Wk, wkb, 4194304);
  f32_to_bf16_k<<<2048, 256, 0, stream>>>(Wv, wvb, 4194304);
  f32_to_bf16_k<<<2048, 256, 0, stream>>>(Wo, wob, 4194304);
  hipMemsetAsync(lwb, 0, 524288, stream);
  f32_to_bf16_k<<<32, 256, 0, stream>>>(lw, lwb, 65536);

  dim3 blk(256);
  dim3 gbig(16, 64);
  gemm_bt<unsigned short><<<gbig, blk, 0, stream>>>(hsb, wqb, XCb, 8192, 2048, 2048);
  gemm_bt<unsigned short><<<gbig, blk, 0, stream>>>(hsb, wkb, XBb, 8192, 2048, 2048);
  gemm_bt<unsigned short><<<gbig, blk, 0, stream>>>(hsb, wvb, XAb, 8192, 2048, 2048);
  gemm_bt<unsigned short><<<dim3(1, 64), blk, 0, stream>>>(hsb, lwb, ilrb, 8192, 128, 2048);
  coeff_k<<<1024, 256, 0, stream>>>(ilrb, lb, coeff);
  ttt_scan<<<128, 256, 0, stream>>>(XCb, XBb, XAb, coeff, lnw, lnb, W1i, b1i, hsb);
  gemm_bt<float><<<gbig, blk, 0, stream>>>(hsb, wob, out, 8192, 2048, 2048);
}

// Round 6
// 857.768 us; speedup vs baseline: 1.0769x; 1.0769x over previous
//
#include <hip/hip_runtime.h>

// ---------------------------------------------------------------------------
// TTT base module: out = (scan(XC,XB,XA,coeff) ) @ Wo^T
//   gemm256: 256x256 tile, BK=32, 8 waves, 3-buffer ring, counted vmcnt(4),
//     ONE barrier per K-tile (stages issued right after barrier, before
//     ds_read+MFMA), setprio'd MFMA clusters, T2 chunk-XOR swizzle
//     (pre-swizzled global source + swizzled ds_read), XCD block swizzle.
//   gemm_bt (128x128, 2-buffer): kept for the N=128 ilr GEMM only.
//   Scan v4: 4 waves, feature-split, 4 raw barriers/chunk (proven at 295us).
// ---------------------------------------------------------------------------

typedef __attribute__((ext_vector_type(4))) float float4v;
typedef __attribute__((ext_vector_type(2))) float float2v;
typedef __attribute__((ext_vector_type(8))) __bf16 bf16x8;
typedef __attribute__((ext_vector_type(4))) short short4v;
typedef __attribute__((ext_vector_type(4))) unsigned int uint4v;
typedef __attribute__((ext_vector_type(2))) unsigned int uint2v;

__device__ __forceinline__ unsigned short f2bf(float f) {
  unsigned int u = __builtin_bit_cast(unsigned int, f);
  u += 0x7FFFu + ((u >> 16) & 1u);
  return (unsigned short)(u >> 16);
}
__device__ __forceinline__ float bf2f(unsigned short s) {
  unsigned int u = ((unsigned int)s) << 16;
  return __builtin_bit_cast(float, u);
}
__device__ __forceinline__ void lds_load16(const void* g, void* l) {
  __builtin_amdgcn_global_load_lds((const __attribute__((address_space(1))) void*)g,
                                   (__attribute__((address_space(3))) void*)l, 16, 0, 0);
}

__device__ __forceinline__ void store_out(float* p, float v) { *p = v; }
__device__ __forceinline__ void store_out(unsigned short* p, float v) { *p = f2bf(v); }

// DPP helpers: VALU-speed cross-lane moves within 16-lane rows.
template <int CTRL>
__device__ __forceinline__ float dppmov(float x) {
  return __builtin_bit_cast(
      float, __builtin_amdgcn_update_dpp(0, __builtin_bit_cast(int, x), CTRL, 0xF, 0xF, true));
}
__device__ __forceinline__ float red16(float x) {
  x += dppmov<0xB1>(x);   // quad_perm xor1
  x += dppmov<0x4E>(x);   // quad_perm xor2
  x += dppmov<0x124>(x);  // row_ror:4
  x += dppmov<0x128>(x);  // row_ror:8
  return x;
}
__device__ __forceinline__ unsigned int cvtpk_bf16(float lo, float hi) {
  unsigned int r;
  asm("v_cvt_pk_bf16_f32 %0, %1, %2" : "=v"(r) : "v"(lo), "v"(hi));
  return r;
}
// Raw workgroup barrier: waits only LDS ops (lgkmcnt), NOT vmcnt.
__device__ __forceinline__ void bar_sync() {
  asm volatile("s_waitcnt lgkmcnt(0)" ::: "memory");
  __builtin_amdgcn_s_barrier();
  asm volatile("" ::: "memory");
}

// ---------------------------------------------------------------------------
// gemm256: C[m,n] = sum_k A[m,k]*B[n,k], 256x256 tile, BK=32, 512 thr.
// Wave grid 2Mx4N; per-wave 128x64 output = acc[8][4]. 3-buffer LDS ring,
// depth-2 staging, one vmcnt(4)+barrier per K-tile.
// ---------------------------------------------------------------------------
template <typename OUT>
__global__ __launch_bounds__(512, 2) void gemm256(
    const unsigned short* __restrict__ A, const unsigned short* __restrict__ B,
    OUT* __restrict__ C, int M, int N, int K) {
  __shared__ unsigned short sA[3][256 * 32];  // lds[row][c] = glob[row][c^(row&3)]
  __shared__ unsigned short sB[3][256 * 32];
  const int tid = threadIdx.x;
  const int wave = tid >> 6;
  const int lane = tid & 63;
  const int quad = lane >> 4;
  const int l15 = lane & 15;
  const int wm = (wave >> 2) * 128;
  const int wn = (wave & 3) * 64;

  // XCD-aware bijective block swizzle (nwg = 256, multiple of 8)
  const int nwg = gridDim.x;
  const int cpx = nwg >> 3;
  const int o = blockIdx.x;
  const int wgid = (o & 7) * cpx + (o >> 3);
  const int nbx = N >> 8;
  const int bm = (wgid / nbx) * 256;
  const int bn = (wgid % nbx) * 256;

  float4v acc[8][4];
#pragma unroll
  for (int i = 0; i < 8; ++i)
#pragma unroll
    for (int j = 0; j < 4; ++j) acc[i][j] = (float4v){0.f, 0.f, 0.f, 0.f};

  // staging: thread t covers row srow=t>>2 (of a 128-row half), 16B chunk
  // pre-swizzled on the SOURCE so linear LDS holds the swizzled layout.
  const int srow = tid >> 2;
  const int schunk = (tid & 3) ^ (srow & 3);
  const unsigned short* aS = A + (size_t)(bm + srow) * K + schunk * 8;
  const unsigned short* bS = B + (size_t)(bn + srow) * K + schunk * 8;
  const size_t hstep = (size_t)128 * K;
  const int ldsw = wave * 512;  // wave-uniform LDS element base within a half

#define STAGE_A(t, bi)                                                \
  {                                                                   \
    lds_load16(aS + (size_t)(t) * 32, &sA[bi][ldsw]);                 \
    lds_load16(aS + (size_t)(t) * 32 + hstep, &sA[bi][4096 + ldsw]);  \
  }
#define STAGE_B(t, bi)                                                \
  {                                                                   \
    lds_load16(bS + (size_t)(t) * 32, &sB[bi][ldsw]);                 \
    lds_load16(bS + (size_t)(t) * 32 + hstep, &sB[bi][4096 + ldsw]);  \
  }

  const int NT = K >> 5;
  // prologue: stage tiles 0 and 1
  STAGE_A(0, 0);
  STAGE_B(0, 0);
  STAGE_A(1, 1);
  STAGE_B(1, 1);

  // per-lane constant swizzled read column (elements); frag rows have
  // row&3 == l15&3, so chunk quad^(l15&3) undoes the source swizzle.
  const int sw = (quad ^ (l15 & 3)) * 8;

  for (int T = 0; T < NT; ++T) {
    const int cur = T % 3;
    const int dst = (T + 2) % 3;
    // boundary: own stage(T) loads landed; tile T+1's 4 stay in flight.
    if (T + 1 < NT) {
      asm volatile("s_waitcnt vmcnt(4)" ::: "memory");
    } else {
      asm volatile("s_waitcnt vmcnt(0)" ::: "memory");
    }
    __builtin_amdgcn_s_barrier();
    asm volatile("" ::: "memory");

    // issue depth-2 stage first: gets a full K-tile of compute for flight
    if (T + 2 < NT) {
      STAGE_A(T + 2, dst);
      STAGE_B(T + 2, dst);
    }

    bf16x8 bfr[4], afr[4];
#pragma unroll
    for (int nt = 0; nt < 4; ++nt)
      bfr[nt] = *(const bf16x8*)&sB[cur][(wn + nt * 16 + l15) * 32 + sw];
#pragma unroll
    for (int mt = 0; mt < 4; ++mt)
      afr[mt] = *(const bf16x8*)&sA[cur][(wm + mt * 16 + l15) * 32 + sw];
    __builtin_amdgcn_s_setprio(1);
#pragma unroll
    for (int mt = 0; mt < 4; ++mt)
#pragma unroll
      for (int nt = 0; nt < 4; ++nt)
        acc[mt][nt] = __builtin_amdgcn_mfma_f32_16x16x32_bf16(afr[mt], bfr[nt], acc[mt][nt], 0, 0, 0);
    __builtin_amdgcn_s_setprio(0);

#pragma unroll
    for (int mt = 0; mt < 4; ++mt)
      afr[mt] = *(const bf16x8*)&sA[cur][(wm + 64 + mt * 16 + l15) * 32 + sw];
    __builtin_amdgcn_s_setprio(1);
#pragma unroll
    for (int mt = 0; mt < 4; ++mt)
#pragma unroll
      for (int nt = 0; nt < 4; ++nt)
        acc[4 + mt][nt] = __builtin_amdgcn_mfma_f32_16x16x32_bf16(afr[mt], bfr[nt], acc[4 + mt][nt], 0, 0, 0);
    __builtin_amdgcn_s_setprio(0);
    asm volatile("" ::: "memory");
  }
#undef STAGE_A
#undef STAGE_B

#pragma unroll
  for (int mt = 0; mt < 8; ++mt) {
    const int row0 = bm + wm + mt * 16 + quad * 4;
#pragma unroll
    for (int nt = 0; nt < 4; ++nt) {
      const int col = bn + wn + nt * 16 + l15;
#pragma unroll
      for (int r = 0; r < 4; ++r)
        store_out(&C[(size_t)(row0 + r) * N + col], acc[mt][nt][r]);
    }
  }
}

// ---------------------------------------------------------------------------
// gemm_bt (128x128, 2-buffer, per-step vmcnt(0)+barrier): ilr GEMM only.
// ---------------------------------------------------------------------------
template <typename OUT>
__global__ __launch_bounds__(256) void gemm_bt(
    const unsigned short* __restrict__ A, const unsigned short* __restrict__ B,
    OUT* __restrict__ C, int M, int N, int K) {
  __shared__ unsigned short sA[2][128 * 32];
  __shared__ unsigned short sB[2][128 * 32];
  const int tid = threadIdx.x;
  const int wave = tid >> 6;
  const int lane = tid & 63;
  const int quad = lane >> 4;
  const int l15 = lane & 15;
  const int wm = (wave >> 1) * 64;
  const int wn = (wave & 1) * 64;
  const int bm = blockIdx.y * 128;
  const int bn = blockIdx.x * 128;

  float4v acc[4][4];
#pragma unroll
  for (int i = 0; i < 4; ++i)
#pragma unroll
    for (int j = 0; j < 4; ++j) acc[i][j] = (float4v){0.f, 0.f, 0.f, 0.f};

  const int srow = tid >> 2;
  const int scol = (tid & 3) * 8;
  const unsigned short* aptr = A + (size_t)(bm + srow) * K + scol;
  const unsigned short* bptr = B + (size_t)(bn + srow) * K + scol;
  const size_t astep = (size_t)64 * K;
  const int woff = wave * 512;

  lds_load16(aptr, &sA[0][woff]);
  lds_load16(aptr + astep, &sA[0][2048 + woff]);
  lds_load16(bptr, &sB[0][woff]);
  lds_load16(bptr + astep, &sB[0][2048 + woff]);
  asm volatile("s_waitcnt vmcnt(0)" ::: "memory");
  __builtin_amdgcn_s_barrier();
  asm volatile("" ::: "memory");

  int cur = 0;
  for (int kt = 0; kt < K; kt += 32) {
    if (kt + 32 < K) {
      const int nxt = cur ^ 1;
      lds_load16(aptr + kt + 32, &sA[nxt][woff]);
      lds_load16(aptr + kt + 32 + astep, &sA[nxt][2048 + woff]);
      lds_load16(bptr + kt + 32, &sB[nxt][woff]);
      lds_load16(bptr + kt + 32 + astep, &sB[nxt][2048 + woff]);
    }
    bf16x8 af[4], bf[4];
#pragma unroll
    for (int i = 0; i < 4; ++i)
      af[i] = *(const bf16x8*)&sA[cur][(wm + i * 16 + l15) * 32 + quad * 8];
#pragma unroll
    for (int j = 0; j < 4; ++j)
      bf[j] = *(const bf16x8*)&sB[cur][(wn + j * 16 + l15) * 32 + quad * 8];
#pragma unroll
    for (int i = 0; i < 4; ++i)
#pragma unroll
      for (int j = 0; j < 4; ++j)
        acc[i][j] = __builtin_amdgcn_mfma_f32_16x16x32_bf16(af[i], bf[j], acc[i][j], 0, 0, 0);
    asm volatile("s_waitcnt vmcnt(0)" ::: "memory");
    __builtin_amdgcn_s_barrier();
    asm volatile("" ::: "memory");
    cur ^= 1;
  }

#pragma unroll
  for (int i = 0; i < 4; ++i) {
    const int row0 = bm + wm + i * 16 + quad * 4;
#pragma unroll
    for (int j = 0; j < 4; ++j) {
      const int col = bn + wn + j * 16 + l15;
#pragma unroll
      for (int r = 0; r < 4; ++r)
        store_out(&C[(size_t)(row0 + r) * N + col], acc[i][j][r]);
    }
  }
}

// ---------------------------------------------------------------------------
__global__ __launch_bounds__(256) void f32_to_bf16_k(const float* __restrict__ s,
                                                     unsigned short* __restrict__ d, int n) {
  const int i = (blockIdx.x * 256 + threadIdx.x) * 8;
  if (i >= n) return;
  const float4v a = *(const float4v*)(s + i);
  const float4v b = *(const float4v*)(s + i + 4);
  uint4v o;
  o[0] = (unsigned int)f2bf(a[0]) | ((unsigned int)f2bf(a[1]) << 16);
  o[1] = (unsigned int)f2bf(a[2]) | ((unsigned int)f2bf(a[3]) << 16);
  o[2] = (unsigned int)f2bf(b[0]) | ((unsigned int)f2bf(b[1]) << 16);
  o[3] = (unsigned int)f2bf(b[2]) | ((unsigned int)f2bf(b[3]) << 16);
  *(uint4v*)(d + i) = o;
}

// ---------------------------------------------------------------------------
__global__ __launch_bounds__(256) void coeff_k(const unsigned short* __restrict__ ilr,
                                               const float* __restrict__ lb,
                                               float* __restrict__ coeff) {
  const int gid = blockIdx.x * 256 + threadIdx.x;
  const int row = gid >> 5;
  const int h = gid & 31;
  const float v = bf2f(ilr[row * 128 + h]) + lb[h];
  const float sig = 1.0f / (1.0f + __expf(-v));
  const int b = row >> 11;
  const int pos = row & 2047;
  const int cc = pos >> 4;
  const int k = pos & 15;
  coeff[((((size_t)b * 32 + h) * 128 + cc) << 4) + k] = sig / (64.0f * (float)(k + 1));
}

// ---------------------------------------------------------------------------
// TTT scan v4: one block = one (b,h); 4 waves; 128 sequential chunks of K=16.
// Wave w owns features w*16..w*16+15.
// ---------------------------------------------------------------------------
__global__ __launch_bounds__(256, 1) void ttt_scan(
    const unsigned short* __restrict__ XC, const unsigned short* __restrict__ XB,
    const unsigned short* __restrict__ XA, const float* __restrict__ coeff,
    const float* __restrict__ lnw, const float* __restrict__ lnb,
    const float* __restrict__ W1i, const float* __restrict__ b1i,
    unsigned short* __restrict__ XCW) {
  const int b = blockIdx.x >> 5;
  const int h = blockIdx.x & 31;
  const int tid = threadIdx.x;
  const int wave = tid >> 6;
  const int lane = tid & 63;
  const int quad = lane >> 4;
  const int l15 = lane & 15;

  constexpr int LDW = 88;
  __shared__ __attribute__((aligned(16))) unsigned short sXC[2][16 * LDW];
  __shared__ __attribute__((aligned(16))) unsigned short sXB[2][16 * LDW];
  __shared__ __attribute__((aligned(16))) unsigned short sXA[2][16 * LDW];
  __shared__ __attribute__((aligned(16))) unsigned short sW1[64 * LDW];
  __shared__ __attribute__((aligned(16))) float sRed[3][16][8];

  const int fcol = wave * 16 + l15;
  const float gam = lnw[h * 64 + fcol];
  const float bet = lnb[h * 64 + fcol];

  float4v W1r[4];
#pragma unroll
  for (int mt = 0; mt < 4; ++mt) {
    float4v v;
#pragma unroll
    for (int r = 0; r < 4; ++r)
      v[r] = W1i[(size_t)h * 4096 + (size_t)(mt * 16 + quad * 4 + r) * 64 + fcol];
    W1r[mt] = v;
  }
  float b1v = b1i[h * 64 + fcol];

#pragma unroll
  for (int mt = 0; mt < 4; ++mt) {
    uint2v p;
    p[0] = cvtpk_bf16(W1r[mt][0], W1r[mt][1]);
    p[1] = cvtpk_bf16(W1r[mt][2], W1r[mt][3]);
    *(uint2v*)&sW1[(size_t)fcol * LDW + mt * 16 + quad * 4] = p;
  }

  const int u = tid & 127;
  const int grow = u >> 3;
  const int gcol = (u & 7) * 8;
  const size_t hdoff = (size_t)h * 64;
  const size_t browoff = (size_t)b * 2048;
  const float* cobase = coeff + (((size_t)b * 32 + h) * 128) * 16;
  const float inv64 = 1.0f / 64.0f;
  const float4v zero4 = {0.f, 0.f, 0.f, 0.f};

  uint4v pA = {0, 0, 0, 0}, pB = {0, 0, 0, 0};
  float4v pcof;
  {
    const size_t goff = (browoff + (size_t)grow) * 2048 + hdoff + gcol;
    if (tid < 128) {
      pA = *(const uint4v*)(XC + goff);
      pB = *(const uint4v*)(XA + goff);
    } else {
      pA = *(const uint4v*)(XB + goff);
    }
    pcof = *(const float4v*)(cobase + quad * 4);
  }

  for (int c = 0; c < 128; ++c) {
    const int buf = c & 1;
    if (tid < 128) {
      *(uint4v*)&sXC[buf][grow * LDW + gcol] = pA;
      *(uint4v*)&sXA[buf][grow * LDW + gcol] = pB;
    } else {
      *(uint4v*)&sXB[buf][grow * LDW + gcol] = pA;
    }
    const float4v cof = pcof;
    bar_sync();  // stage(c) + W1 publish visible

    {
      const int cn = (c < 127) ? c + 1 : 127;
      const size_t goff = (browoff + (size_t)(cn * 16 + grow)) * 2048 + hdoff + gcol;
      if (tid < 128) {
        pA = *(const uint4v*)(XC + goff);
        pB = *(const uint4v*)(XA + goff);
      } else {
        pA = *(const uint4v*)(XB + goff);
      }
      pcof = *(const float4v*)(cobase + (size_t)cn * 16 + quad * 4);
    }

    bf16x8 xbf[2], xcf[2], w1f[2];
#pragma unroll
    for (int hh = 0; hh < 2; ++hh) {
      xbf[hh] = *(const bf16x8*)&sXB[buf][l15 * LDW + hh * 32 + quad * 8];
      xcf[hh] = *(const bf16x8*)&sXC[buf][l15 * LDW + hh * 32 + quad * 8];
      w1f[hh] = *(const bf16x8*)&sW1[(size_t)fcol * LDW + hh * 32 + quad * 8];
    }

    float4v z = __builtin_amdgcn_mfma_f32_16x16x32_bf16(xbf[0], w1f[0], zero4, 0, 0, 0);
    z = __builtin_amdgcn_mfma_f32_16x16x32_bf16(xbf[1], w1f[1], z, 0, 0, 0);
#pragma unroll
    for (int r = 0; r < 4; ++r) z[r] += b1v;

    float s1p[4], s2p[4];
#pragma unroll
    for (int r = 0; r < 4; ++r) {
      s1p[r] = red16(z[r]);
      s2p[r] = red16(z[r] * z[r]);
    }
    if (l15 == 0) {
#pragma unroll
      for (int r = 0; r < 4; ++r)
        *(float2v*)&sRed[0][quad * 4 + r][wave * 2] = (float2v){s1p[r], s2p[r]};
    }

    float4v at = __builtin_amdgcn_mfma_f32_16x16x32_bf16(xbf[0], xcf[0], zero4, 0, 0, 0);
    at = __builtin_amdgcn_mfma_f32_16x16x32_bf16(xbf[1], xcf[1], at, 0, 0, 0);

    bar_sync();  // red1 partials visible

    float mu[4], rstd[4];
#pragma unroll
    for (int r = 0; r < 4; ++r) {
      const float4v v0 = *(const float4v*)&sRed[0][quad * 4 + r][0];
      const float4v v1 = *(const float4v*)&sRed[0][quad * 4 + r][4];
      const float s1 = v0[0] + v0[2] + v1[0] + v1[2];
      const float s2 = v0[1] + v0[3] + v1[1] + v1[3];
      mu[r] = s1 * inv64;
      rstd[r] = rsqrtf(s2 * inv64 - mu[r] * mu[r] + 1e-6f);
    }
    float xh[4], gg[4];
#pragma unroll
    for (int r = 0; r < 4; ++r) {
      xh[r] = (z[r] - mu[r]) * rstd[r];
      const int toff = (quad * 4 + r) * LDW + fcol;
      const float tgt = bf2f(sXA[buf][toff]) - bf2f(sXB[buf][toff]);
      gg[r] = (gam * xh[r] + bet - tgt) * gam;
    }
    float sgp[4], sgxp[4];
#pragma unroll
    for (int r = 0; r < 4; ++r) {
      sgp[r] = red16(gg[r]);
      sgxp[r] = red16(gg[r] * xh[r]);
    }
    if (l15 == 0) {
#pragma unroll
      for (int r = 0; r < 4; ++r)
        *(float2v*)&sRed[1][quad * 4 + r][wave * 2] = (float2v){sgp[r], sgxp[r]};
    }

    short4v caf[4];
#pragma unroll
    for (int mt = 0; mt < 4; ++mt)
#pragma unroll
      for (int jj = 0; jj < 4; ++jj)
        caf[mt][jj] =
            (short)f2bf(-cof[jj] * bf2f(sXB[buf][(quad * 4 + jj) * LDW + mt * 16 + l15]));
    short4v m1f;
#pragma unroll
    for (int jj = 0; jj < 4; ++jj) {
      const int k = quad * 4 + jj;
      const float e = (k <= l15) ? cof[jj] : 0.0f;
      m1f[jj] = (short)f2bf(-(at[jj] + 1.0f) * e);
    }

    bar_sync();  // red2 partials visible

    float grad[4];
    short4v gradb;
#pragma unroll
    for (int r = 0; r < 4; ++r) {
      const float4v v0 = *(const float4v*)&sRed[1][quad * 4 + r][0];
      const float4v v1 = *(const float4v*)&sRed[1][quad * 4 + r][4];
      const float sg = v0[0] + v0[2] + v1[0] + v1[2];
      const float sgx = v0[1] + v0[3] + v1[1] + v1[3];
      grad[r] = (64.0f * gg[r] - sg - xh[r] * sgx) * (rstd[r] * inv64);
      gradb[r] = (short)f2bf(grad[r]);
    }

    float4v zb = __builtin_amdgcn_mfma_f32_16x16x32_bf16(xcf[0], w1f[0], zero4, 0, 0, 0);
    zb = __builtin_amdgcn_mfma_f32_16x16x32_bf16(xcf[1], w1f[1], zb, 0, 0, 0);
    zb = __builtin_amdgcn_mfma_f32_16x16x16bf16_1k(m1f, gradb, zb, 0, 0, 0);
#pragma unroll
    for (int r = 0; r < 4; ++r) zb[r] += b1v;

#pragma unroll
    for (int r = 0; r < 4; ++r) {
      s1p[r] = red16(zb[r]);
      s2p[r] = red16(zb[r] * zb[r]);
    }
    if (l15 == 0) {
#pragma unroll
      for (int r = 0; r < 4; ++r)
        *(float2v*)&sRed[2][quad * 4 + r][wave * 2] = (float2v){s1p[r], s2p[r]};
    }

    {
      float pb = cof[0] * grad[0] + cof[1] * grad[1] + cof[2] * grad[2] + cof[3] * grad[3];
      pb += __shfl_xor(pb, 16);
      pb += __shfl_xor(pb, 32);
      b1v -= pb;
    }
#pragma unroll
    for (int mt = 0; mt < 4; ++mt)
      W1r[mt] = __builtin_amdgcn_mfma_f32_16x16x16bf16_1k(caf[mt], gradb, W1r[mt], 0, 0, 0);

    bar_sync();  // red3 partials visible

#pragma unroll
    for (int r = 0; r < 4; ++r) {
      const float4v v0 = *(const float4v*)&sRed[2][quad * 4 + r][0];
      const float4v v1 = *(const float4v*)&sRed[2][quad * 4 + r][4];
      const float s1 = v0[0] + v0[2] + v1[0] + v1[2];
      const float s2 = v0[1] + v0[3] + v1[1] + v1[3];
      const float mu2 = s1 * inv64;
      const float rstd2 = rsqrtf(s2 * inv64 - mu2 * mu2 + 1e-6f);
      const float xhat = (zb[r] - mu2) * rstd2;
      const float y = gam * xhat + bet;
      const float o = bf2f(sXC[buf][(quad * 4 + r) * LDW + fcol]) + y;
      XCW[(browoff + (size_t)(c * 16 + quad * 4 + r)) * 2048 + hdoff + fcol] = f2bf(o);
    }

#pragma unroll
    for (int mt = 0; mt < 4; ++mt) {
      uint2v p;
      p[0] = cvtpk_bf16(W1r[mt][0], W1r[mt][1]);
      p[1] = cvtpk_bf16(W1r[mt][2], W1r[mt][3]);
      *(uint2v*)&sW1[(size_t)fcol * LDW + mt * 16 + quad * 4] = p;
    }
  }
}

// ---------------------------------------------------------------------------
extern "C" void kernel_launch(void* const* d_in, const int* in_sizes, int n_in,
                              void* d_out, int out_size, void* d_ws, size_t ws_size,
                              hipStream_t stream) {
  const float* hs = (const float*)d_in[0];
  const float* Wq = (const float*)d_in[1];
  const float* Wk = (const float*)d_in[2];
  const float* Wv = (const float*)d_in[3];
  const float* Wo = (const float*)d_in[4];
  const float* lw = (const float*)d_in[5];
  const float* lb = (const float*)d_in[6];
  const float* lnw = (const float*)d_in[7];
  const float* lnb = (const float*)d_in[8];
  const float* W1i = (const float*)d_in[9];
  const float* b1i = (const float*)d_in[10];
  float* out = (float*)d_out;
  char* ws = (char*)d_ws;

  unsigned short* hsb = (unsigned short*)(ws);               // 33554432 (hs bf16; reused as XCW)
  unsigned short* wqb = (unsigned short*)(ws + 33554432);    // 8388608
  unsigned short* wkb = (unsigned short*)(ws + 41943040);    // 8388608
  unsigned short* wvb = (unsigned short*)(ws + 50331648);    // 8388608
  unsigned short* wob = (unsigned short*)(ws + 58720256);    // 8388608
  unsigned short* lwb = (unsigned short*)(ws + 67108864);    // 524288
  unsigned short* XCb = (unsigned short*)(ws + 67633152);    // 33554432
  unsigned short* XBb = (unsigned short*)(ws + 101187584);   // 33554432
  unsigned short* XAb = (unsigned short*)(ws + 134742016);   // 33554432
  unsigned short* ilrb = (unsigned short*)(ws + 168296448);  // 2097152
  float* coeff = (float*)(ws + 170393600);                   // 1048576

  f32_to_bf16_k<<<8192, 256, 0, stream>>>(hs, hsb, 16777216);
  f32_to_bf16_k<<<2048, 256, 0, stream>>>(Wq, wqb, 4194304);
  f32_to_bf16_k<<<2048, 256, 0, stream>>>(Wk, wkb, 4194304);
  f32_to_bf16_k<<<2048, 256, 0, stream>>>(Wv, wvb, 4194304);
  f32_to_bf16_k<<<2048, 256, 0, stream>>>(Wo, wob, 4194304);
  hipMemsetAsync(lwb, 0, 524288, stream);
  f32_to_bf16_k<<<32, 256, 0, stream>>>(lw, lwb, 65536);

  gemm256<unsigned short><<<256, 512, 0, stream>>>(hsb, wqb, XCb, 8192, 2048, 2048);
  gemm256<unsigned short><<<256, 512, 0, stream>>>(hsb, wkb, XBb, 8192, 2048, 2048);
  gemm256<unsigned short><<<256, 512, 0, stream>>>(hsb, wvb, XAb, 8192, 2048, 2048);
  gemm_bt<unsigned short><<<dim3(1, 64), dim3(256), 0, stream>>>(hsb, lwb, ilrb, 8192, 128, 2048);
  coeff_k<<<1024, 256, 0, stream>>>(ilrb, lb, coeff);
  ttt_scan<<<128, 256, 0, stream>>>(XCb, XBb, XAb, coeff, lnw, lnb, W1i, b1i, hsb);
  gemm256<float><<<256, 512, 0, stream>>>(hsb, wob, out, 8192, 2048, 2048);
}